// Round 8
// baseline (363.294 us; speedup 1.0000x reference)
//
#include <hip/hip_runtime.h>
#include <math.h>

#define Bdim 8
#define Sdim 1024
#define Hdim 1024
#define NHd 16
#define HDd 64
#define N3H 3072

// ws layout (ushort elements)
// Q: [bh][s][128] row-major (hi|lo). K: [bh][16 tiles][8192] fragment-ordered.
// V: [bh][16 tiles][4096] fragment-ordered. W^T hi/lo fragment-ordered planes after.
#define Q_OFF   0u
#define K_OFF   16777216u
#define V_OFF   33554432u
#define WH_OFF  41943040u
#define WL_OFF  45088768u
// d_out scratch layout (ushort elements): Ahi, Alo (fragment-ordered)
#define AHI_OFF 0u
#define ALO_OFF 8388608u

typedef __bf16 bf16x8 __attribute__((ext_vector_type(8)));
typedef float  f32x4  __attribute__((ext_vector_type(4)));

__device__ __forceinline__ unsigned short f2bf(float x) {
  unsigned b = __builtin_bit_cast(unsigned, x);
  return (unsigned short)((b + 0x7FFFu + ((b >> 16) & 1u)) >> 16);
}
__device__ __forceinline__ float bf2f(unsigned short h) {
  unsigned b = ((unsigned)h) << 16;
  return __builtin_bit_cast(float, b);
}
__device__ __forceinline__ void split_hl(float v, unsigned short& h, unsigned short& l) {
  h = f2bf(v);
  l = f2bf(v - bf2f(h));
}
__device__ __forceinline__ void async16(void* lds, const void* g) {
  __builtin_amdgcn_global_load_lds((const __attribute__((address_space(1))) unsigned int*)g,
                                   (__attribute__((address_space(3))) unsigned int*)lds, 16, 0, 0);
}

// Fragment-ordered plane index for a [rows][1024] matrix tiled 128x32:
// tile (rt=row>>7, kt=k>>5) at (rt*32+kt)*4096; within tile:
// chunk = ((row>>4)&7)*4 + ((k>>3)&3), then *16 + (row&15), element k&7.
__device__ __forceinline__ size_t frag_idx(int row, int k) {
  return ((size_t)((row >> 7) * 32 + (k >> 5)) << 12)
       + ((size_t)((((row >> 4) & 7) * 4 + ((k >> 3) & 3)) * 16 + (row & 15)) << 3)
       + (k & 7);
}

// ---------- fused convert: A -> frag-ordered hi/lo planes (d_out scratch); W -> W^T frag-ordered hi/lo (ws) ----------
__global__ __launch_bounds__(256) void convert_AW(
    const float* __restrict__ A, const float* __restrict__ W,
    unsigned short* __restrict__ aout, unsigned short* __restrict__ ws)
{
  __shared__ float T[64][65];
  const int tid = threadIdx.x;
  int bid = blockIdx.x;
  if (bid < 4096) {
    size_t i = ((size_t)bid * 256 + tid) * 8;   // 8 consecutive k of one row
    int row = (int)(i >> 10);
    int k   = (int)(i & 1023);
    float4 a0 = *(const float4*)&A[i];
    float4 a1 = *(const float4*)&A[i + 4];
    float av[8] = {a0.x, a0.y, a0.z, a0.w, a1.x, a1.y, a1.z, a1.w};
    unsigned short h[8], l[8];
    #pragma unroll
    for (int j = 0; j < 8; ++j) split_hl(av[j], h[j], l[j]);
    size_t dst = frag_idx(row, k);
    *(uint4*)&aout[AHI_OFF + dst] = *(uint4*)h;
    *(uint4*)&aout[ALO_OFF + dst] = *(uint4*)l;
    return;
  }
  bid -= 4096;
  const int n0 = (bid % (N3H / 64)) * 64;
  const int k0 = (bid / (N3H / 64)) * 64;
  #pragma unroll
  for (int r = 0; r < 4; ++r) {
    int k = r * 16 + (tid >> 4);
    int n = (tid & 15) * 4;
    float4 v = *(const float4*)&W[(size_t)(k0 + k) * N3H + n0 + n];
    T[k][n + 0] = v.x; T[k][n + 1] = v.y; T[k][n + 2] = v.z; T[k][n + 3] = v.w;
  }
  __syncthreads();
  int n = tid >> 2;           // 0..63 local col
  int kl = (tid & 3) * 16;    // 0,16,32,48 local k
  unsigned short h[16], l[16];
  #pragma unroll
  for (int i = 0; i < 16; ++i) split_hl(T[kl + i][n], h[i], l[i]);
  size_t d0 = frag_idx(n0 + n, k0 + kl);
  size_t d1 = frag_idx(n0 + n, k0 + kl + 8);
  *(uint4*)&ws[WH_OFF + d0] = *(uint4*)&h[0];
  *(uint4*)&ws[WH_OFF + d1] = *(uint4*)&h[8];
  *(uint4*)&ws[WL_OFF + d0] = *(uint4*)&l[0];
  *(uint4*)&ws[WL_OFF + d1] = *(uint4*)&l[8];
}

// ---------- MFMA QKV GEMM: C = A(8192x1024) * W(1024x3072) + bias ----------
// Fragment-ordered staging (conflict-free ds_read_b128); V-columns use 2 terms.
__global__ __launch_bounds__(256, 3) void qkv_mfma(
    const unsigned short* __restrict__ ao,
    const unsigned short* __restrict__ ws,
    const float* __restrict__ bias,
    unsigned short* __restrict__ wso)
{
  __shared__ unsigned short sA0[4096], sA1[4096];
  __shared__ unsigned short sB0[4096], sB1[4096];

  const int tid  = threadIdx.x;
  const int wave = tid >> 6;
  const int lane = tid & 63;
  const int l16  = lane & 15;
  const int quad = lane >> 4;

  const int n0 = blockIdx.x * 128;
  const int m0 = blockIdx.y * 128;
  const int wm = (wave >> 1) * 64;
  const int wn = (wave & 1) * 64;

  const unsigned short* Ah = ao + AHI_OFF;
  const unsigned short* Al = ao + ALO_OFF;
  const unsigned short* Wh = ws + WH_OFF;
  const unsigned short* Wl = ws + WL_OFF;

  // which (q/k/v) of this wave's 64 output cols — wave-uniform
  const int mywhich = (2 * blockIdx.x + (wave & 1)) % 3;
  const bool needs3 = (mywhich < 2);

  f32x4 acc[4][4];
  #pragma unroll
  for (int i = 0; i < 4; ++i)
    #pragma unroll
    for (int j = 0; j < 4; ++j) acc[i][j] = (f32x4){0.f, 0.f, 0.f, 0.f};

  for (int ktile = 0; ktile < 32; ++ktile) {
    __syncthreads();
    {
      size_t baseA = ((size_t)(blockIdx.y * 32 + ktile)) << 12;
      size_t baseB = ((size_t)(blockIdx.x * 32 + ktile)) << 12;
      #pragma unroll
      for (int r = 0; r < 2; ++r) {
        int c = r * 256 + tid;
        async16(&sA0[c * 8], &Ah[baseA + (size_t)c * 8]);
        async16(&sA1[c * 8], &Al[baseA + (size_t)c * 8]);
        async16(&sB0[c * 8], &Wh[baseB + (size_t)c * 8]);
        async16(&sB1[c * 8], &Wl[baseB + (size_t)c * 8]);
      }
    }
    __syncthreads();

    bf16x8 af[4][2], bf[4][2];
    #pragma unroll
    for (int i = 0; i < 4; ++i) {
      int rb = (wm >> 4) + i;
      af[i][0] = *(const bf16x8*)&sA0[(rb * 64 + lane) * 8];
      af[i][1] = *(const bf16x8*)&sA1[(rb * 64 + lane) * 8];
    }
    #pragma unroll
    for (int j = 0; j < 4; ++j) {
      int rb = (wn >> 4) + j;
      bf[j][0] = *(const bf16x8*)&sB0[(rb * 64 + lane) * 8];
      bf[j][1] = *(const bf16x8*)&sB1[(rb * 64 + lane) * 8];
    }
    #pragma unroll
    for (int i = 0; i < 4; ++i)
      #pragma unroll
      for (int j = 0; j < 4; ++j) {
        acc[i][j] = __builtin_amdgcn_mfma_f32_16x16x32_bf16(af[i][0], bf[j][0], acc[i][j], 0, 0, 0);
        acc[i][j] = __builtin_amdgcn_mfma_f32_16x16x32_bf16(af[i][1], bf[j][0], acc[i][j], 0, 0, 0);
      }
    if (needs3) {
      #pragma unroll
      for (int i = 0; i < 4; ++i)
        #pragma unroll
        for (int j = 0; j < 4; ++j)
          acc[i][j] = __builtin_amdgcn_mfma_f32_16x16x32_bf16(af[i][0], bf[j][1], acc[i][j], 0, 0, 0);
    }
  }

  const int ncol0 = n0 + wn;
  const int which = mywhich;
  const int head  = ncol0 / 192;
  const int mrow0 = m0 + wm;
  const int bb = mrow0 >> 10;
  const int sb = mrow0 & 1023;
  const int bh = bb * NHd + head;

  float bs[4];
  #pragma unroll
  for (int j = 0; j < 4; ++j) bs[j] = bias[ncol0 + j * 16 + l16];

  if (which == 0) {
    unsigned short* dst = wso + Q_OFF + ((size_t)bh * Sdim + sb) * 128;
    #pragma unroll
    for (int i = 0; i < 4; ++i)
      #pragma unroll
      for (int j = 0; j < 4; ++j) {
        int d = j * 16 + l16;
        #pragma unroll
        for (int r = 0; r < 4; ++r) {
          int s = i * 16 + quad * 4 + r;
          unsigned short h, l;
          split_hl(acc[i][j][r] + bs[j], h, l);
          dst[(size_t)s * 128 + d]      = h;
          dst[(size_t)s * 128 + 64 + d] = l;
        }
      }
  } else if (which == 1) {
    unsigned short* dst = wso + K_OFF + (size_t)bh * 131072 + (size_t)(sb >> 6) * 8192;
    #pragma unroll
    for (int i = 0; i < 4; ++i)
      #pragma unroll
      for (int j = 0; j < 4; ++j) {
        int c = j * 16 + l16;
        #pragma unroll
        for (int r = 0; r < 4; ++r) {
          int sp = i * 16 + quad * 4 + r;
          int idx = ((((sp >> 4) * 4 + (c >> 5)) * 64 + ((c >> 3) & 3) * 16 + (sp & 15)) << 3) + (c & 7);
          unsigned short h, l;
          split_hl(acc[i][j][r] + bs[j], h, l);
          dst[idx]        = h;
          dst[idx + 1024] = l;
        }
      }
  } else {
    unsigned short* dst = wso + V_OFF + (size_t)bh * 65536 + (size_t)(sb >> 6) * 4096;
    #pragma unroll
    for (int i = 0; i < 4; ++i)
      #pragma unroll
      for (int j = 0; j < 4; ++j) {
        int dr = j * 16 + l16;
        int ky = i * 16 + quad * 4;
        int idx = ((((dr >> 4) * 2 + (ky >> 5)) * 64 + ((ky >> 3) & 3) * 16 + (dr & 15)) << 3) + (ky & 7);
        unsigned short p[4];
        #pragma unroll
        for (int r = 0; r < 4; ++r) p[r] = f2bf(acc[i][j][r] + bs[j]);
        *(uint2*)&dst[idx] = *(uint2*)p;
      }
  }
}

// -------- MFMA flash attention: 64 q/block, single-buffer async staging, 4 blk/CU --------
__global__ __launch_bounds__(256, 4) void attn_mfma(
    const unsigned short* __restrict__ qhl,
    const unsigned short* __restrict__ khl,   // fragment-ordered tiles
    const unsigned short* __restrict__ vt,    // fragment-ordered tiles
    const int* __restrict__ mask,
    float* __restrict__ out)
{
  __shared__ unsigned short Ks[8192];
  __shared__ unsigned short Vs[4096];
  __shared__ unsigned short Pw[4][1024];
  __shared__ float msks[1024];

  const int tid  = threadIdx.x;
  const int wave = tid >> 6;
  const int lane = tid & 63;
  const int l16  = lane & 15;
  const int quad = lane >> 4;

  const int bh = blockIdx.x & 127;
  const int qt = blockIdx.x >> 7;
  const int bb = bh >> 4;
  const int q0 = qt * 64;

  const unsigned short* kplane = khl + (size_t)bh * 131072;
  const unsigned short* vplane = vt  + (size_t)bh * 65536;

  {
    int4 mv = *(const int4*)&mask[bb * Sdim + tid * 4];
    msks[tid * 4 + 0] = mv.x ? 1.f : 0.f;
    msks[tid * 4 + 1] = mv.y ? 1.f : 0.f;
    msks[tid * 4 + 2] = mv.z ? 1.f : 0.f;
    msks[tid * 4 + 3] = mv.w ? 1.f : 0.f;
  }

  bf16x8 qf[4];
  {
    int row = q0 + wave * 16 + l16;
    const unsigned short* src = qhl + ((size_t)bh * Sdim + row) * 128;
    #pragma unroll
    for (int kk = 0; kk < 4; ++kk)
      qf[kk] = *(const bf16x8*)&src[kk * 32 + quad * 8];
  }

  f32x4 O[4] = {{0.f,0.f,0.f,0.f},{0.f,0.f,0.f,0.f},{0.f,0.f,0.f,0.f},{0.f,0.f,0.f,0.f}};
  float mrow[4] = {-INFINITY, -INFINITY, -INFINITY, -INFINITY};
  float lrow[4] = {0.f, 0.f, 0.f, 0.f};

  #pragma unroll 1
  for (int kt = 0; kt < 16; ++kt) {
    __syncthreads();
    {
      const unsigned short* ksrc = kplane + (size_t)kt * 8192;
      const unsigned short* vsrc = vplane + (size_t)kt * 4096;
      #pragma unroll
      for (int r = 0; r < 4; ++r)
        async16(&Ks[(r * 256 + tid) * 8], &ksrc[(size_t)(r * 256 + tid) * 8]);
      #pragma unroll
      for (int r = 0; r < 2; ++r)
        async16(&Vs[(r * 256 + tid) * 8], &vsrc[(size_t)(r * 256 + tid) * 8]);
    }
    __syncthreads();

    f32x4 sc[4];
    #pragma unroll
    for (int ns = 0; ns < 4; ++ns) {
      f32x4 c = {0.f, 0.f, 0.f, 0.f};
      bf16x8 kf0 = *(const bf16x8*)&Ks[((ns * 4 + 0) * 64 + lane) * 8];
      bf16x8 kf1 = *(const bf16x8*)&Ks[((ns * 4 + 1) * 64 + lane) * 8];
      bf16x8 kf2 = *(const bf16x8*)&Ks[((ns * 4 + 2) * 64 + lane) * 8];
      bf16x8 kf3 = *(const bf16x8*)&Ks[((ns * 4 + 3) * 64 + lane) * 8];
      c = __builtin_amdgcn_mfma_f32_16x16x32_bf16(qf[0], kf0, c, 0, 0, 0);
      c = __builtin_amdgcn_mfma_f32_16x16x32_bf16(qf[1], kf1, c, 0, 0, 0);
      c = __builtin_amdgcn_mfma_f32_16x16x32_bf16(qf[2], kf0, c, 0, 0, 0);
      c = __builtin_amdgcn_mfma_f32_16x16x32_bf16(qf[3], kf1, c, 0, 0, 0);
      c = __builtin_amdgcn_mfma_f32_16x16x32_bf16(qf[0], kf2, c, 0, 0, 0);
      c = __builtin_amdgcn_mfma_f32_16x16x32_bf16(qf[1], kf3, c, 0, 0, 0);
      sc[ns] = c;
    }

    float rmax[4] = {-INFINITY, -INFINITY, -INFINITY, -INFINITY};
    #pragma unroll
    for (int ns = 0; ns < 4; ++ns) {
      float mk = msks[kt * 64 + ns * 16 + l16];
      #pragma unroll
      for (int r = 0; r < 4; ++r) {
        float s = (mk != 0.f) ? -10000.f : sc[ns][r] * 8.f;
        sc[ns][r] = s;
        rmax[r] = fmaxf(rmax[r], s);
      }
    }
    #pragma unroll
    for (int r = 0; r < 4; ++r) {
      float v = rmax[r];
      v = fmaxf(v, __shfl_xor(v, 1, 16));
      v = fmaxf(v, __shfl_xor(v, 2, 16));
      v = fmaxf(v, __shfl_xor(v, 4, 16));
      v = fmaxf(v, __shfl_xor(v, 8, 16));
      rmax[r] = v;
    }

    float alpha[4];
    #pragma unroll
    for (int r = 0; r < 4; ++r) {
      float mn = fmaxf(mrow[r], rmax[r]);
      alpha[r] = __expf(mrow[r] - mn);
      mrow[r] = mn;
      lrow[r] *= alpha[r];
    }
    #pragma unroll
    for (int d = 0; d < 4; ++d)
      #pragma unroll
      for (int r = 0; r < 4; ++r) O[d][r] *= alpha[r];

    float rsum[4] = {0.f, 0.f, 0.f, 0.f};
    #pragma unroll
    for (int ns = 0; ns < 4; ++ns) {
      int key = ns * 16 + l16;
      int cbase = (((key >> 5) * 4 + ((key >> 3) & 3)) * 16 + quad * 4) * 8 + (key & 7);
      #pragma unroll
      for (int r = 0; r < 4; ++r) {
        float p = __expf(sc[ns][r] - mrow[r]);
        rsum[r] += p;
        Pw[wave][cbase + r * 8] = f2bf(p);
      }
    }
    #pragma unroll
    for (int r = 0; r < 4; ++r) {
      float v = rsum[r];
      v += __shfl_xor(v, 1, 16);
      v += __shfl_xor(v, 2, 16);
      v += __shfl_xor(v, 4, 16);
      v += __shfl_xor(v, 8, 16);
      lrow[r] += v;
    }

    bf16x8 pf[2];
    #pragma unroll
    for (int kk = 0; kk < 2; ++kk)
      pf[kk] = *(const bf16x8*)&Pw[wave][((kk * 4 + quad) * 16 + l16) * 8];
    #pragma unroll
    for (int d = 0; d < 4; ++d)
      #pragma unroll
      for (int kk = 0; kk < 2; ++kk) {
        bf16x8 vf = *(const bf16x8*)&Vs[((d * 2 + kk) * 64 + lane) * 8];
        O[d] = __builtin_amdgcn_mfma_f32_16x16x32_bf16(pf[kk], vf, O[d], 0, 0, 0);
      }
  }

  const int h = bh & 15;
  #pragma unroll
  for (int r = 0; r < 4; ++r) {
    float inv = 1.f / lrow[r];
    int q = q0 + wave * 16 + quad * 4 + r;
    float* dst = out + ((size_t)bb * Sdim + q) * Hdim + h * HDd;
    #pragma unroll
    for (int d = 0; d < 4; ++d)
      dst[d * 16 + l16] = O[d][r] * inv;
  }
}

extern "C" void kernel_launch(void* const* d_in, const int* in_sizes, int n_in,
                              void* d_out, int out_size, void* d_ws, size_t ws_size,
                              hipStream_t stream) {
  const float* hs   = (const float*)d_in[0];
  const int*   mask = (const int*)d_in[1];
  const float* w    = (const float*)d_in[2];
  const float* bias = (const float*)d_in[3];
  float* out = (float*)d_out;
  unsigned short* ws = (unsigned short*)d_ws;
  unsigned short* ao = (unsigned short*)d_out;   // A hi/lo scratch, overwritten by attn

  convert_AW<<<4096 + (N3H / 64) * (1024 / 64), 256, 0, stream>>>(hs, w, ao, ws);

  qkv_mfma<<<dim3(N3H / 128, 8192 / 128), 256, 0, stream>>>(ao, ws, bias, ws);

  attn_mfma<<<Bdim * NHd * (Sdim / 64), 256, 0, stream>>>(
      ws + Q_OFF, ws + K_OFF, ws + V_OFF, mask, out);
}